// Round 14
// baseline (397.916 us; speedup 1.0000x reference)
//
#include <hip/hip_runtime.h>
#include <hip/hip_fp8.h>

typedef __bf16 bf16_t;
typedef __bf16 bf16x8 __attribute__((ext_vector_type(8)));
typedef __bf16 bf16x4 __attribute__((ext_vector_type(4)));
typedef float  f32x4  __attribute__((ext_vector_type(4)));
typedef float  f32x2  __attribute__((ext_vector_type(2)));

#define D_FEAT 512
#define M_TILES 196            // 196*256 = 50176 rows (padded)
#define NPAD2 (M_TILES * 256)
#define N_TILES 4              // 512 / 128
#define GEMM_BLOCKS (M_TILES * N_TILES)  // 784 = 8*98
#define XBLOCKS (NPAD2 / 4)    // 12544 blocks for x-conversion

__device__ __forceinline__ float fp8_to_f32(unsigned int b) {
  __hip_fp8_e4m3 q;
  q.__x = (__hip_fp8_storage_t)b;
  return (float)q;
}
__device__ __forceinline__ unsigned char f32_to_fp8(float v) {
  __hip_fp8_e4m3 q(v);
  return (unsigned char)q.__x;
}

// ------- fused: x -> bf16 (padded) [+ fp8 copy] + both weight matrices + degree histogram -------
__global__ void cvt_all_k(const float* __restrict__ x, bf16_t* __restrict__ xb,
                          unsigned char* __restrict__ x8, int valid,
                          const float* __restrict__ Wl1, const float* __restrict__ Wr1,
                          bf16_t* __restrict__ WB1,
                          const float* __restrict__ Wl2, const float* __restrict__ Wr2,
                          bf16_t* __restrict__ WB2,
                          const int* __restrict__ dst, int* __restrict__ deg, int E) {
  int b = blockIdx.x;
  bf16x8 o;
  if (b < XBLOCKS) {
    int idx = (b * 256 + threadIdx.x) * 8;
    float e[8];
    if (idx < valid) {
      const float4* p = (const float4*)(x + idx);
      float4 a = p[0], c = p[1];
      e[0] = a.x; e[1] = a.y; e[2] = a.z; e[3] = a.w;
      e[4] = c.x; e[5] = c.y; e[6] = c.z; e[7] = c.w;
    } else {
#pragma unroll
      for (int i = 0; i < 8; ++i) e[i] = 0.f;
    }
#pragma unroll
    for (int i = 0; i < 8; ++i) o[i] = (bf16_t)e[i];
    *(bf16x8*)(xb + idx) = o;
    if (x8) {
      unsigned int lo = 0, hi = 0;
#pragma unroll
      for (int i = 0; i < 4; ++i) lo |= (unsigned int)f32_to_fp8(e[i]) << (8 * i);
#pragma unroll
      for (int i = 0; i < 4; ++i) hi |= (unsigned int)f32_to_fp8(e[4 + i]) << (8 * i);
      uint2 pk; pk.x = lo; pk.y = hi;
      *(uint2*)(x8 + idx) = pk;
    }
  } else if (b < XBLOCKS + 512) {
    int wb = b - XBLOCKS;  // 0..511
    const float* Wl = (wb < 256) ? Wl1 : Wl2;
    const float* Wr = (wb < 256) ? Wr1 : Wr2;
    bf16_t* WB = (wb < 256) ? WB1 : WB2;
    int idx = ((wb & 255) * 256 + threadIdx.x) * 8;  // into [512][1024]
    int n = idx >> 10, k = idx & 1023;
    const float* s = (k < 512) ? (Wl + n * 512 + k) : (Wr + n * 512 + k - 512);
    const float4* p = (const float4*)s;
    float4 a = p[0], c = p[1];
    o[0] = (bf16_t)a.x; o[1] = (bf16_t)a.y; o[2] = (bf16_t)a.z; o[3] = (bf16_t)a.w;
    o[4] = (bf16_t)c.x; o[5] = (bf16_t)c.y; o[6] = (bf16_t)c.z; o[7] = (bf16_t)c.w;
    *(bf16x8*)(WB + idx) = o;
  } else {
    // degree histogram (deg pre-zeroed by memset earlier in stream)
    int e = (b - XBLOCKS - 512) * 256 + threadIdx.x;
    if (e < E) atomicAdd(&deg[dst[e]], 1);
  }
}

// ---------------- CSR build ----------------
__global__ void scan_part_k(const int* __restrict__ deg, int* __restrict__ partial, int N) {
  __shared__ int sd[512];
  int tid = threadIdx.x;
  int i = blockIdx.x * 512 + tid;
  sd[tid] = (i < N) ? deg[i] : 0;
  __syncthreads();
  for (int s = 256; s > 0; s >>= 1) {
    if (tid < s) sd[tid] += sd[tid + s];
    __syncthreads();
  }
  if (tid == 0) partial[blockIdx.x] = sd[0];
}

// fused: block-level scan of raw partials (redundant per block, 98 elems) + per-elem scan
__global__ void scan_blk2_k(const int* __restrict__ deg, const int* __restrict__ partial,
                            int* __restrict__ rowS, int* __restrict__ cursor, int N, int nb) {
  __shared__ int sp[128];
  __shared__ int sd[512];
  int tid = threadIdx.x;
  if (tid < 128) sp[tid] = (tid < nb) ? partial[tid] : 0;
  __syncthreads();
#pragma unroll
  for (int off = 1; off < 128; off <<= 1) {
    int t = (tid >= off && tid < 128) ? sp[tid - off] : 0;
    __syncthreads();
    if (tid < 128) sp[tid] += t;
    __syncthreads();
  }
  // sp = inclusive scan of raw partials
  const int blkoff = sp[blockIdx.x] - partial[blockIdx.x];  // exclusive offset of this block
  int i = blockIdx.x * 512 + tid;
  int v = (i < N) ? deg[i] : 0;
  sd[tid] = v;
  __syncthreads();
  for (int offd = 1; offd < 512; offd <<= 1) {
    int t = (tid >= offd) ? sd[tid - offd] : 0;
    __syncthreads();
    sd[tid] += t;
    __syncthreads();
  }
  int excl = sd[tid] - v + blkoff;
  if (i < N) { rowS[i] = excl; cursor[i] = excl; }
  if (blockIdx.x == 0 && tid == 0) rowS[N] = sp[nb - 1];
}

__global__ void scat_k(const int* __restrict__ src, const int* __restrict__ dst,
                       int* __restrict__ cursor, int* __restrict__ col, int E) {
  int e = blockIdx.x * 256 + threadIdx.x;
  if (e < E) {
    int d = dst[e];
    int p = atomicAdd(&cursor[d], 1);
    col[p] = src[e];
  }
}

// ---------------- mean aggregation (fp8 gather, f32 accumulate, HW decode) ----------------
template <bool FP8>
__global__ __launch_bounds__(256) void agg_k(const void* __restrict__ Xv,
                                             const int* __restrict__ rs,
                                             const int* __restrict__ col,
                                             bf16_t* __restrict__ out,
                                             int N) {
  const int lane = threadIdx.x & 63;
  const int node = blockIdx.x * 4 + (threadIdx.x >> 6);
  const size_t obase = (size_t)node * D_FEAT + lane * 8;
  bf16x8 o;
  if (node >= N) {
#pragma unroll
    for (int i = 0; i < 8; ++i) o[i] = (bf16_t)0.f;
    *(bf16x8*)(out + obase) = o;
    return;
  }
  const int s = rs[node], e = rs[node + 1];
  float acc[8] = {0.f, 0.f, 0.f, 0.f, 0.f, 0.f, 0.f, 0.f};
  int j = s;
  if (FP8) {
    const unsigned char* X8 = (const unsigned char*)Xv;
    const int loff = lane * 8;
    auto addv = [&](uint2 v) {
#if __has_builtin(__builtin_amdgcn_cvt_pk_f32_fp8)
      f32x2 p0 = __builtin_amdgcn_cvt_pk_f32_fp8((int)v.x, false);
      f32x2 p1 = __builtin_amdgcn_cvt_pk_f32_fp8((int)v.x, true);
      f32x2 p2 = __builtin_amdgcn_cvt_pk_f32_fp8((int)v.y, false);
      f32x2 p3 = __builtin_amdgcn_cvt_pk_f32_fp8((int)v.y, true);
      acc[0] += p0[0]; acc[1] += p0[1]; acc[2] += p1[0]; acc[3] += p1[1];
      acc[4] += p2[0]; acc[5] += p2[1]; acc[6] += p3[0]; acc[7] += p3[1];
#else
#pragma unroll
      for (int i = 0; i < 4; ++i) acc[i] += fp8_to_f32((v.x >> (8 * i)) & 0xff);
#pragma unroll
      for (int i = 0; i < 4; ++i) acc[4 + i] += fp8_to_f32((v.y >> (8 * i)) & 0xff);
#endif
    };
    for (; j + 8 <= e; j += 8) {
      int c0 = col[j + 0], c1 = col[j + 1], c2 = col[j + 2], c3 = col[j + 3];
      int c4 = col[j + 4], c5 = col[j + 5], c6 = col[j + 6], c7 = col[j + 7];
      uint2 v0 = *(const uint2*)(X8 + (size_t)c0 * D_FEAT + loff);
      uint2 v1 = *(const uint2*)(X8 + (size_t)c1 * D_FEAT + loff);
      uint2 v2 = *(const uint2*)(X8 + (size_t)c2 * D_FEAT + loff);
      uint2 v3 = *(const uint2*)(X8 + (size_t)c3 * D_FEAT + loff);
      uint2 v4 = *(const uint2*)(X8 + (size_t)c4 * D_FEAT + loff);
      uint2 v5 = *(const uint2*)(X8 + (size_t)c5 * D_FEAT + loff);
      uint2 v6 = *(const uint2*)(X8 + (size_t)c6 * D_FEAT + loff);
      uint2 v7 = *(const uint2*)(X8 + (size_t)c7 * D_FEAT + loff);
      addv(v0); addv(v1); addv(v2); addv(v3);
      addv(v4); addv(v5); addv(v6); addv(v7);
    }
    for (; j < e; ++j) {
      uint2 v = *(const uint2*)(X8 + (size_t)col[j] * D_FEAT + loff);
      addv(v);
    }
  } else {
    const bf16_t* X = (const bf16_t*)Xv;
    const int loff = lane * 8;
    for (; j + 8 <= e; j += 8) {
      int c0 = col[j + 0], c1 = col[j + 1], c2 = col[j + 2], c3 = col[j + 3];
      int c4 = col[j + 4], c5 = col[j + 5], c6 = col[j + 6], c7 = col[j + 7];
      bf16x8 v0 = *(const bf16x8*)(X + (size_t)c0 * D_FEAT + loff);
      bf16x8 v1 = *(const bf16x8*)(X + (size_t)c1 * D_FEAT + loff);
      bf16x8 v2 = *(const bf16x8*)(X + (size_t)c2 * D_FEAT + loff);
      bf16x8 v3 = *(const bf16x8*)(X + (size_t)c3 * D_FEAT + loff);
      bf16x8 v4 = *(const bf16x8*)(X + (size_t)c4 * D_FEAT + loff);
      bf16x8 v5 = *(const bf16x8*)(X + (size_t)c5 * D_FEAT + loff);
      bf16x8 v6 = *(const bf16x8*)(X + (size_t)c6 * D_FEAT + loff);
      bf16x8 v7 = *(const bf16x8*)(X + (size_t)c7 * D_FEAT + loff);
#pragma unroll
      for (int i = 0; i < 8; ++i) {
        float s01 = (float)v0[i] + (float)v1[i];
        float s23 = (float)v2[i] + (float)v3[i];
        float s45 = (float)v4[i] + (float)v5[i];
        float s67 = (float)v6[i] + (float)v7[i];
        acc[i] += (s01 + s23) + (s45 + s67);
      }
    }
    for (; j < e; ++j) {
      bf16x8 v0 = *(const bf16x8*)(X + (size_t)col[j] * D_FEAT + loff);
#pragma unroll
      for (int i = 0; i < 8; ++i) acc[i] += (float)v0[i];
    }
  }
  float sc = (e > s) ? 1.0f / (float)(e - s) : 0.f;
#pragma unroll
  for (int i = 0; i < 8; ++i) o[i] = (bf16_t)(acc[i] * sc);
  *(bf16x8*)(out + obase) = o;
}

// ---------------- fused GEMM: BM=256 x BN=128, BK=32, 8 waves (4Mx2N, wave 64x64) ----------------
// Counted-vmcnt double-buffer (vmcnt(3): next tile's 3 loads stay in flight).
// K-loop LDS 48KB; epilogue overlay 70KB -> 2 blocks/CU (16 waves/CU).
// Swizzle: LDS[row][s] holds global k-chunk s ^ ((row>>1)&3); read slot = g ^ ((fr>>1)&3)
// -> per-16-lane b128 phase each bank hit exactly 2x (free). (R8's fr&3 bug corrected.)
__device__ __forceinline__ void gload_lds16(const void* g, void* l) {
  __builtin_amdgcn_global_load_lds(
      (const __attribute__((address_space(1))) unsigned int*)g,
      (__attribute__((address_space(3))) unsigned int*)l,
      16, 0, 0);
}

template <bool RELU, bool HAS8, typename OT>
__global__ __launch_bounds__(512, 4) void gemm_k(
    const bf16_t* __restrict__ A0,   // K 0..511   (mean features), NPAD2 rows
    const bf16_t* __restrict__ A1,   // K 512..1023 (self features), NPAD2 rows
    const bf16_t* __restrict__ WB,   // [512][1024]
    const float* __restrict__ bias,  // [512]
    OT* __restrict__ out,
    unsigned char* __restrict__ out8,  // fp8 copy (HAS8 only)
    int M) {
  // XCD-chunked bijective remap: 784 blocks = 8 XCDs x 98.
  const int t = (blockIdx.x & 7) * (GEMM_BLOCKS / 8) + (blockIdx.x >> 3);
  const int mt = t >> 2;
  const int nt = t & 3;

  // K-loop: 2 bufs x (A 256x32 + B 128x32) ushorts = 2 x 12288 us = 48KB.
  // Epilogue overlay: [256][68] f32 = 69632B. Union -> 69888B.
  __shared__ __align__(16) unsigned char smemraw[69888];
  unsigned short* smem = (unsigned short*)smemraw;

  const int tid = threadIdx.x;
  const int lane = tid & 63;
  const int wave = tid >> 6;     // 0..7
  const int wm = wave >> 1;      // 0..3
  const int wn = wave & 1;       // 0..1
  const int m0 = mt * 256;
  const int n0 = nt * 128;

  f32x4 acc[4][4];
#pragma unroll
  for (int m = 0; m < 4; ++m)
#pragma unroll
    for (int n = 0; n < 4; ++n) acc[m][n] = (f32x4){0.f, 0.f, 0.f, 0.f};

  // ---- staging geometry (512 threads) ----
  const int srow = tid >> 2;            // 0..127
  const int sslot = tid & 3;            // 0..3 (16B slots per 64B k-row)
  const int kc = sslot ^ ((srow >> 1) & 3);  // global k-chunk this lane fetches
  const int ldsOffA = srow * 32 + sslot * 8;  // ushort idx (also B offset)
  size_t gA[2], gB;
#pragma unroll
  for (int l = 0; l < 2; ++l)
    gA[l] = (size_t)(m0 + l * 128 + srow) * 1024 + kc * 16;  // A row stride 1024B
  gB = (size_t)(n0 + srow) * 2048 + kc * 16;                 // WB row stride 2048B

  auto stage = [&](int buf, int kk) {
    unsigned short* sA = smem + buf * 12288;
    unsigned short* sB = sA + 8192;
    const int k0 = kk * 32;
    const char* Ab = (k0 < 512) ? (const char*)A0 : (const char*)A1;
    const size_t ka = (size_t)(k0 & 511) * 2;
    const size_t kb = (size_t)k0 * 2;
    gload_lds16(Ab + gA[0] + ka, sA + ldsOffA);
    gload_lds16(Ab + gA[1] + ka, sA + 4096 + ldsOffA);
    gload_lds16((const char*)WB + gB + kb, sB + ldsOffA);
  };

  // ---- fragment-read offsets ----
  const int fr = lane & 15;
  const int g = lane >> 4;
  const int sl = (g ^ ((fr >> 1) & 3)) * 8;
  int rdA[4], rdB[4];
#pragma unroll
  for (int m = 0; m < 4; ++m) rdA[m] = (wm * 64 + m * 16 + fr) * 32 + sl;
#pragma unroll
  for (int n = 0; n < 4; ++n) rdB[n] = (wn * 64 + n * 16 + fr) * 32 + sl;

  // ---- prologue: 2 tiles in flight (6 loads/thread outstanding) ----
  stage(0, 0);
  stage(1, 1);
  __builtin_amdgcn_sched_barrier(0);

  const int NK = 32;  // K=1024 / BK=32
  for (int kk = 0; kk < NK; ++kk) {
    const int cur = kk & 1;
    if (kk < NK - 1) {
      asm volatile("s_waitcnt vmcnt(3)" ::: "memory");
    } else {
      asm volatile("s_waitcnt vmcnt(0)" ::: "memory");
    }
    __builtin_amdgcn_sched_barrier(0);
    __builtin_amdgcn_s_barrier();      // all waves' tile-kk loads landed
    __builtin_amdgcn_sched_barrier(0);

    unsigned short* sA = smem + cur * 12288;
    unsigned short* sB = sA + 8192;
    bf16x8 aF[4], bF[4];
    __builtin_amdgcn_s_setprio(1);
#pragma unroll
    for (int m = 0; m < 4; ++m) aF[m] = *(const bf16x8*)(sA + rdA[m]);
#pragma unroll
    for (int n = 0; n < 4; ++n) bF[n] = *(const bf16x8*)(sB + rdB[n]);
#pragma unroll
    for (int m = 0; m < 4; ++m)
#pragma unroll
      for (int n = 0; n < 4; ++n)
        acc[m][n] = __builtin_amdgcn_mfma_f32_16x16x32_bf16(aF[m], bF[n], acc[m][n], 0, 0, 0);
    __builtin_amdgcn_s_setprio(0);

    __builtin_amdgcn_sched_barrier(0);
    __builtin_amdgcn_s_barrier();      // all waves done reading buf[cur]
    __builtin_amdgcn_sched_barrier(0);
    if (kk + 2 < NK) stage(cur, kk + 2);
    __builtin_amdgcn_sched_barrier(0);
  }

  // ---- epilogue: LDS-staged, coalesced (two 64-col halves) ----
  float bv[4];
#pragma unroll
  for (int n = 0; n < 4; ++n) bv[n] = bias[n0 + wn * 64 + n * 16 + fr];

  OT* sE = (OT*)smemraw;  // [256][68] padded
#pragma unroll
  for (int h = 0; h < 2; ++h) {
    __syncthreads();
    if (wn == h) {
#pragma unroll
      for (int n = 0; n < 4; ++n) {
        const int colL = n * 16 + fr;  // 0..63 within half
#pragma unroll
        for (int m = 0; m < 4; ++m) {
          const int rbase = wm * 64 + m * 16 + g * 4;
#pragma unroll
          for (int r = 0; r < 4; ++r) {
            float v = acc[m][n][r] + bv[n];
            if (RELU) v = fmaxf(v, 0.f);
            sE[(rbase + r) * 68 + colL] = (OT)v;
          }
        }
      }
    }
    __syncthreads();
    // drain: 8 passes, 32 rows/pass; lane covers 4 consecutive cols
    const int rL0 = tid >> 4;          // 0..31
    const int colL = (tid & 15) * 4;   // 0..60
    const int gcol = n0 + h * 64 + colL;
#pragma unroll
    for (int p = 0; p < 8; ++p) {
      const int rowL = p * 32 + rL0;
      const int grow = m0 + rowL;
      if (grow < M) {
        if constexpr (sizeof(OT) == 4) {
          f32x4 v = *(const f32x4*)&sE[rowL * 68 + colL];
          *(f32x4*)((float*)out + (size_t)grow * 512 + gcol) = v;
        } else {
          bf16x4 v = *(const bf16x4*)&sE[rowL * 68 + colL];
          *(bf16x4*)((bf16_t*)out + (size_t)grow * 512 + gcol) = v;
          if (HAS8) {
            unsigned int u = 0;
#pragma unroll
            for (int i = 0; i < 4; ++i)
              u |= (unsigned int)f32_to_fp8((float)v[i]) << (8 * i);
            *(unsigned int*)(out8 + (size_t)grow * 512 + gcol) = u;
          }
        }
      }
    }
  }
}

extern "C" void kernel_launch(void* const* d_in, const int* in_sizes, int n_in,
                              void* d_out, int out_size, void* d_ws, size_t ws_size,
                              hipStream_t stream) {
  const float* x   = (const float*)d_in[0];
  const int*   ei  = (const int*)d_in[1];
  const float* Wl1 = (const float*)d_in[2];
  const float* Wr1 = (const float*)d_in[3];
  const float* b1  = (const float*)d_in[4];
  const float* Wl2 = (const float*)d_in[5];
  const float* Wr2 = (const float*)d_in[6];
  const float* b2  = (const float*)d_in[7];

  const int N = in_sizes[0] / 512;            // 50000
  const int E = in_sizes[1] / 2;              // 800000
  const int* srcp = ei;
  const int* dstp = ei + E;

  char* ws = (char*)d_ws;
  size_t off = 0;
  auto alloc = [&](size_t sz) -> char* {
    char* p = ws + off;
    off += sz;
    off = (off + 255) & ~(size_t)255;
    return p;
  };

  bf16_t* xb    = (bf16_t*)alloc((size_t)NPAD2 * 512 * 2);
  bf16_t* hb    = (bf16_t*)alloc((size_t)NPAD2 * 512 * 2);
  bf16_t* meanb = (bf16_t*)alloc((size_t)NPAD2 * 512 * 2);
  bf16_t* WB1   = (bf16_t*)alloc((size_t)512 * 1024 * 2);
  bf16_t* WB2   = (bf16_t*)alloc((size_t)512 * 1024 * 2);
  int* deg      = (int*)alloc((size_t)N * 4);
  int* rowS     = (int*)alloc((size_t)(N + 8) * 4);
  int* cursor   = (int*)alloc((size_t)N * 4);
  int* partial  = (int*)alloc(4096);
  int* colb     = (int*)alloc((size_t)E * 4);
  unsigned char* x8 = (unsigned char*)alloc((size_t)NPAD2 * 512);
  unsigned char* h8 = (unsigned char*)alloc((size_t)NPAD2 * 512);
  const bool useFp8 = (off <= ws_size);
  (void)n_in; (void)out_size;

  hipMemsetAsync(deg, 0, (size_t)N * 4, stream);

  const int degBlocks = (E + 255) / 256;  // 3125
  cvt_all_k<<<dim3(XBLOCKS + 512 + degBlocks), dim3(256), 0, stream>>>(
      x, xb, useFp8 ? x8 : nullptr, N * 512, Wl1, Wr1, WB1, Wl2, Wr2, WB2,
      dstp, deg, E);

  int NB = (N + 511) / 512;  // 98
  scan_part_k<<<dim3(NB), dim3(512), 0, stream>>>(deg, partial, N);
  scan_blk2_k<<<dim3(NB), dim3(512), 0, stream>>>(deg, partial, rowS, cursor, N, NB);
  scat_k<<<dim3((E + 255) / 256), dim3(256), 0, stream>>>(srcp, dstp, cursor, colb, E);

  dim3 agrid(NPAD2 / 4);
  dim3 grid(GEMM_BLOCKS);

  if (useFp8) {
    // layer 1 (gemm writes bf16 h AND packed fp8 h8 via coalesced epilogue)
    agg_k<true><<<agrid, dim3(256), 0, stream>>>(x8, rowS, colb, meanb, N);
    gemm_k<true, true, bf16_t><<<grid, dim3(512), 0, stream>>>(meanb, xb, WB1, b1, hb, h8, NPAD2);
    // layer 2
    agg_k<true><<<agrid, dim3(256), 0, stream>>>(h8, rowS, colb, meanb, N);
    gemm_k<false, false, float><<<grid, dim3(512), 0, stream>>>(meanb, hb, WB2, b2, (float*)d_out, nullptr, N);
  } else {
    // fallback: bf16 gather path
    agg_k<false><<<agrid, dim3(256), 0, stream>>>(xb, rowS, colb, meanb, N);
    gemm_k<true, false, bf16_t><<<grid, dim3(512), 0, stream>>>(meanb, xb, WB1, b1, hb, nullptr, NPAD2);
    agg_k<false><<<agrid, dim3(256), 0, stream>>>(hb, rowS, colb, meanb, N);
    gemm_k<false, false, float><<<grid, dim3(512), 0, stream>>>(meanb, hb, WB2, b2, (float*)d_out, nullptr, N);
  }
}

// Round 15
// 387.157 us; speedup vs baseline: 1.0278x; 1.0278x over previous
//
#include <hip/hip_runtime.h>
#include <hip/hip_fp8.h>

typedef __bf16 bf16_t;
typedef __bf16 bf16x8 __attribute__((ext_vector_type(8)));
typedef __bf16 bf16x4 __attribute__((ext_vector_type(4)));
typedef float  f32x4  __attribute__((ext_vector_type(4)));
typedef float  f32x2  __attribute__((ext_vector_type(2)));

#define D_FEAT 512
#define M_TILES 392            // 392*128 = 50176 rows (padded)
#define NPAD2 (M_TILES * 128)
#define N_TILES 4              // 512 / 128
#define GEMM_BLOCKS (M_TILES * N_TILES)  // 1568 = 8*196
#define XBLOCKS (NPAD2 / 4)    // 12544 blocks for x-conversion

__device__ __forceinline__ float fp8_to_f32(unsigned int b) {
  __hip_fp8_e4m3 q;
  q.__x = (__hip_fp8_storage_t)b;
  return (float)q;
}
__device__ __forceinline__ unsigned char f32_to_fp8(float v) {
  __hip_fp8_e4m3 q(v);
  return (unsigned char)q.__x;
}

// ------- fused: x -> bf16 (padded) [+ fp8 copy] + both weight matrices + degree histogram -------
__global__ void cvt_all_k(const float* __restrict__ x, bf16_t* __restrict__ xb,
                          unsigned char* __restrict__ x8, int valid,
                          const float* __restrict__ Wl1, const float* __restrict__ Wr1,
                          bf16_t* __restrict__ WB1,
                          const float* __restrict__ Wl2, const float* __restrict__ Wr2,
                          bf16_t* __restrict__ WB2,
                          const int* __restrict__ dst, int* __restrict__ deg, int E) {
  int b = blockIdx.x;
  bf16x8 o;
  if (b < XBLOCKS) {
    int idx = (b * 256 + threadIdx.x) * 8;
    float e[8];
    if (idx < valid) {
      const float4* p = (const float4*)(x + idx);
      float4 a = p[0], c = p[1];
      e[0] = a.x; e[1] = a.y; e[2] = a.z; e[3] = a.w;
      e[4] = c.x; e[5] = c.y; e[6] = c.z; e[7] = c.w;
    } else {
#pragma unroll
      for (int i = 0; i < 8; ++i) e[i] = 0.f;
    }
#pragma unroll
    for (int i = 0; i < 8; ++i) o[i] = (bf16_t)e[i];
    *(bf16x8*)(xb + idx) = o;
    if (x8) {
      unsigned int lo = 0, hi = 0;
#pragma unroll
      for (int i = 0; i < 4; ++i) lo |= (unsigned int)f32_to_fp8(e[i]) << (8 * i);
#pragma unroll
      for (int i = 0; i < 4; ++i) hi |= (unsigned int)f32_to_fp8(e[4 + i]) << (8 * i);
      uint2 pk; pk.x = lo; pk.y = hi;
      *(uint2*)(x8 + idx) = pk;
    }
  } else if (b < XBLOCKS + 512) {
    int wb = b - XBLOCKS;  // 0..511
    const float* Wl = (wb < 256) ? Wl1 : Wl2;
    const float* Wr = (wb < 256) ? Wr1 : Wr2;
    bf16_t* WB = (wb < 256) ? WB1 : WB2;
    int idx = ((wb & 255) * 256 + threadIdx.x) * 8;  // into [512][1024]
    int n = idx >> 10, k = idx & 1023;
    const float* s = (k < 512) ? (Wl + n * 512 + k) : (Wr + n * 512 + k - 512);
    const float4* p = (const float4*)s;
    float4 a = p[0], c = p[1];
    o[0] = (bf16_t)a.x; o[1] = (bf16_t)a.y; o[2] = (bf16_t)a.z; o[3] = (bf16_t)a.w;
    o[4] = (bf16_t)c.x; o[5] = (bf16_t)c.y; o[6] = (bf16_t)c.z; o[7] = (bf16_t)c.w;
    *(bf16x8*)(WB + idx) = o;
  } else {
    // degree histogram (deg pre-zeroed by memset earlier in stream)
    int e = (b - XBLOCKS - 512) * 256 + threadIdx.x;
    if (e < E) atomicAdd(&deg[dst[e]], 1);
  }
}

// ---------------- CSR build ----------------
__global__ void scan_part_k(const int* __restrict__ deg, int* __restrict__ partial, int N) {
  __shared__ int sd[512];
  int tid = threadIdx.x;
  int i = blockIdx.x * 512 + tid;
  sd[tid] = (i < N) ? deg[i] : 0;
  __syncthreads();
  for (int s = 256; s > 0; s >>= 1) {
    if (tid < s) sd[tid] += sd[tid + s];
    __syncthreads();
  }
  if (tid == 0) partial[blockIdx.x] = sd[0];
}

// fused: block-level scan of raw partials (redundant per block, 98 elems) + per-elem scan
__global__ void scan_blk2_k(const int* __restrict__ deg, const int* __restrict__ partial,
                            int* __restrict__ rowS, int* __restrict__ cursor, int N, int nb) {
  __shared__ int sp[128];
  __shared__ int sd[512];
  int tid = threadIdx.x;
  if (tid < 128) sp[tid] = (tid < nb) ? partial[tid] : 0;
  __syncthreads();
#pragma unroll
  for (int off = 1; off < 128; off <<= 1) {
    int t = (tid >= off && tid < 128) ? sp[tid - off] : 0;
    __syncthreads();
    if (tid < 128) sp[tid] += t;
    __syncthreads();
  }
  // sp = inclusive scan of raw partials
  const int blkoff = sp[blockIdx.x] - partial[blockIdx.x];  // exclusive offset of this block
  int i = blockIdx.x * 512 + tid;
  int v = (i < N) ? deg[i] : 0;
  sd[tid] = v;
  __syncthreads();
  for (int offd = 1; offd < 512; offd <<= 1) {
    int t = (tid >= offd) ? sd[tid - offd] : 0;
    __syncthreads();
    sd[tid] += t;
    __syncthreads();
  }
  int excl = sd[tid] - v + blkoff;
  if (i < N) { rowS[i] = excl; cursor[i] = excl; }
  if (blockIdx.x == 0 && tid == 0) rowS[N] = sp[nb - 1];
}

__global__ void scat_k(const int* __restrict__ src, const int* __restrict__ dst,
                       int* __restrict__ cursor, int* __restrict__ col, int E) {
  int e = blockIdx.x * 256 + threadIdx.x;
  if (e < E) {
    int d = dst[e];
    int p = atomicAdd(&cursor[d], 1);
    col[p] = src[e];
  }
}

// ---------------- mean aggregation (fp8 gather, f32 accumulate, HW decode) ----------------
template <bool FP8>
__global__ __launch_bounds__(256) void agg_k(const void* __restrict__ Xv,
                                             const int* __restrict__ rs,
                                             const int* __restrict__ col,
                                             bf16_t* __restrict__ out,
                                             int N) {
  const int lane = threadIdx.x & 63;
  const int node = blockIdx.x * 4 + (threadIdx.x >> 6);
  const size_t obase = (size_t)node * D_FEAT + lane * 8;
  bf16x8 o;
  if (node >= N) {
#pragma unroll
    for (int i = 0; i < 8; ++i) o[i] = (bf16_t)0.f;
    *(bf16x8*)(out + obase) = o;
    return;
  }
  const int s = rs[node], e = rs[node + 1];
  float acc[8] = {0.f, 0.f, 0.f, 0.f, 0.f, 0.f, 0.f, 0.f};
  int j = s;
  if (FP8) {
    const unsigned char* X8 = (const unsigned char*)Xv;
    const int loff = lane * 8;
    auto addv = [&](uint2 v) {
#if __has_builtin(__builtin_amdgcn_cvt_pk_f32_fp8)
      f32x2 p0 = __builtin_amdgcn_cvt_pk_f32_fp8((int)v.x, false);
      f32x2 p1 = __builtin_amdgcn_cvt_pk_f32_fp8((int)v.x, true);
      f32x2 p2 = __builtin_amdgcn_cvt_pk_f32_fp8((int)v.y, false);
      f32x2 p3 = __builtin_amdgcn_cvt_pk_f32_fp8((int)v.y, true);
      acc[0] += p0[0]; acc[1] += p0[1]; acc[2] += p1[0]; acc[3] += p1[1];
      acc[4] += p2[0]; acc[5] += p2[1]; acc[6] += p3[0]; acc[7] += p3[1];
#else
#pragma unroll
      for (int i = 0; i < 4; ++i) acc[i] += fp8_to_f32((v.x >> (8 * i)) & 0xff);
#pragma unroll
      for (int i = 0; i < 4; ++i) acc[4 + i] += fp8_to_f32((v.y >> (8 * i)) & 0xff);
#endif
    };
    for (; j + 8 <= e; j += 8) {
      int c0 = col[j + 0], c1 = col[j + 1], c2 = col[j + 2], c3 = col[j + 3];
      int c4 = col[j + 4], c5 = col[j + 5], c6 = col[j + 6], c7 = col[j + 7];
      uint2 v0 = *(const uint2*)(X8 + (size_t)c0 * D_FEAT + loff);
      uint2 v1 = *(const uint2*)(X8 + (size_t)c1 * D_FEAT + loff);
      uint2 v2 = *(const uint2*)(X8 + (size_t)c2 * D_FEAT + loff);
      uint2 v3 = *(const uint2*)(X8 + (size_t)c3 * D_FEAT + loff);
      uint2 v4 = *(const uint2*)(X8 + (size_t)c4 * D_FEAT + loff);
      uint2 v5 = *(const uint2*)(X8 + (size_t)c5 * D_FEAT + loff);
      uint2 v6 = *(const uint2*)(X8 + (size_t)c6 * D_FEAT + loff);
      uint2 v7 = *(const uint2*)(X8 + (size_t)c7 * D_FEAT + loff);
      addv(v0); addv(v1); addv(v2); addv(v3);
      addv(v4); addv(v5); addv(v6); addv(v7);
    }
    for (; j < e; ++j) {
      uint2 v = *(const uint2*)(X8 + (size_t)col[j] * D_FEAT + loff);
      addv(v);
    }
  } else {
    const bf16_t* X = (const bf16_t*)Xv;
    const int loff = lane * 8;
    for (; j + 8 <= e; j += 8) {
      int c0 = col[j + 0], c1 = col[j + 1], c2 = col[j + 2], c3 = col[j + 3];
      int c4 = col[j + 4], c5 = col[j + 5], c6 = col[j + 6], c7 = col[j + 7];
      bf16x8 v0 = *(const bf16x8*)(X + (size_t)c0 * D_FEAT + loff);
      bf16x8 v1 = *(const bf16x8*)(X + (size_t)c1 * D_FEAT + loff);
      bf16x8 v2 = *(const bf16x8*)(X + (size_t)c2 * D_FEAT + loff);
      bf16x8 v3 = *(const bf16x8*)(X + (size_t)c3 * D_FEAT + loff);
      bf16x8 v4 = *(const bf16x8*)(X + (size_t)c4 * D_FEAT + loff);
      bf16x8 v5 = *(const bf16x8*)(X + (size_t)c5 * D_FEAT + loff);
      bf16x8 v6 = *(const bf16x8*)(X + (size_t)c6 * D_FEAT + loff);
      bf16x8 v7 = *(const bf16x8*)(X + (size_t)c7 * D_FEAT + loff);
#pragma unroll
      for (int i = 0; i < 8; ++i) {
        float s01 = (float)v0[i] + (float)v1[i];
        float s23 = (float)v2[i] + (float)v3[i];
        float s45 = (float)v4[i] + (float)v5[i];
        float s67 = (float)v6[i] + (float)v7[i];
        acc[i] += (s01 + s23) + (s45 + s67);
      }
    }
    for (; j < e; ++j) {
      bf16x8 v0 = *(const bf16x8*)(X + (size_t)col[j] * D_FEAT + loff);
#pragma unroll
      for (int i = 0; i < 8; ++i) acc[i] += (float)v0[i];
    }
  }
  float sc = (e > s) ? 1.0f / (float)(e - s) : 0.f;
#pragma unroll
  for (int i = 0; i < 8; ++i) o[i] = (bf16_t)(acc[i] * sc);
  *(bf16x8*)(out + obase) = o;
}

// ---------------- fused GEMM (R13-verified best: 128x128, BK=64, 4 waves) ----------------
// Counted-vmcnt double-buffer; LDS-staged coalesced epilogue.
__device__ __forceinline__ void gload_lds16(const void* g, void* l) {
  __builtin_amdgcn_global_load_lds(
      (const __attribute__((address_space(1))) unsigned int*)g,
      (__attribute__((address_space(3))) unsigned int*)l,
      16, 0, 0);
}

template <bool RELU, bool HAS8, typename OT>
__global__ __launch_bounds__(256, 2) void gemm_k(
    const bf16_t* __restrict__ A0,   // K 0..511   (mean features), NPAD2 rows
    const bf16_t* __restrict__ A1,   // K 512..1023 (self features), NPAD2 rows
    const bf16_t* __restrict__ WB,   // [512][1024]
    const float* __restrict__ bias,  // [512]
    OT* __restrict__ out,
    unsigned char* __restrict__ out8,  // fp8 copy (HAS8 only)
    int M) {
  const int t = (blockIdx.x & 7) * (GEMM_BLOCKS / 8) + (blockIdx.x >> 3);
  const int mt = t >> 2;
  const int nt = t & 3;

  __shared__ __align__(16) unsigned short smem[2 * 16384];

  const int tid = threadIdx.x;
  const int lane = tid & 63;
  const int wave = tid >> 6;
  const int wr = wave >> 1;
  const int wc = wave & 1;
  const int m0 = mt * 128;
  const int n0 = nt * 128;

  f32x4 acc[4][4];
#pragma unroll
  for (int m = 0; m < 4; ++m)
#pragma unroll
    for (int n = 0; n < 4; ++n) acc[m][n] = (f32x4){0.f, 0.f, 0.f, 0.f};

  const int srow = tid >> 3;
  const int sslot = tid & 7;
  const int kc = sslot ^ (srow & 7);
  const int ldsOff = srow * 64 + sslot * 8;
  size_t gA[4], gB[4];
#pragma unroll
  for (int l = 0; l < 4; ++l) {
    gA[l] = (size_t)(m0 + l * 32 + srow) * 1024 + kc * 16;
    gB[l] = (size_t)(n0 + l * 32 + srow) * 2048 + kc * 16;
  }

  auto stage = [&](int buf, int kk) {
    unsigned short* sA = smem + buf * 16384;
    unsigned short* sB = sA + 8192;
    const int k0 = kk * 64;
    const char* Ab = (k0 < 512) ? (const char*)A0 : (const char*)A1;
    const size_t ka = (size_t)(k0 & 511) * 2;
    const size_t kb = (size_t)k0 * 2;
#pragma unroll
    for (int l = 0; l < 4; ++l) {
      gload_lds16(Ab + gA[l] + ka, sA + ldsOff + l * 2048);
      gload_lds16((const char*)WB + gB[l] + kb, sB + ldsOff + l * 2048);
    }
  };

  const int fr = lane & 15;
  const int g = lane >> 4;
  int rdA[2][4], rdB[2][4];
#pragma unroll
  for (int ks = 0; ks < 2; ++ks) {
    const int sl = ((ks * 4 + g) ^ (fr & 7)) * 8;
#pragma unroll
    for (int m = 0; m < 4; ++m) rdA[ks][m] = (wr * 64 + m * 16 + fr) * 64 + sl;
#pragma unroll
    for (int n = 0; n < 4; ++n) rdB[ks][n] = (wc * 64 + n * 16 + fr) * 64 + sl;
  }

  stage(0, 0);
  stage(1, 1);
  __builtin_amdgcn_sched_barrier(0);

  const int NK = 16;  // K=1024 / BK=64
  for (int kk = 0; kk < NK; ++kk) {
    const int cur = kk & 1;
    if (kk < NK - 1) {
      asm volatile("s_waitcnt vmcnt(8)" ::: "memory");
    } else {
      asm volatile("s_waitcnt vmcnt(0)" ::: "memory");
    }
    __builtin_amdgcn_sched_barrier(0);
    __builtin_amdgcn_s_barrier();
    __builtin_amdgcn_sched_barrier(0);

    unsigned short* sA = smem + cur * 16384;
    unsigned short* sB = sA + 8192;
    __builtin_amdgcn_s_setprio(1);
#pragma unroll
    for (int ks = 0; ks < 2; ++ks) {
      bf16x8 aF[4], bF[4];
#pragma unroll
      for (int m = 0; m < 4; ++m) aF[m] = *(const bf16x8*)(sA + rdA[ks][m]);
#pragma unroll
      for (int n = 0; n < 4; ++n) bF[n] = *(const bf16x8*)(sB + rdB[ks][n]);
#pragma unroll
      for (int m = 0; m < 4; ++m)
#pragma unroll
        for (int n = 0; n < 4; ++n)
          acc[m][n] = __builtin_amdgcn_mfma_f32_16x16x32_bf16(aF[m], bF[n], acc[m][n], 0, 0, 0);
    }
    __builtin_amdgcn_s_setprio(0);

    __builtin_amdgcn_sched_barrier(0);
    __builtin_amdgcn_s_barrier();
    __builtin_amdgcn_sched_barrier(0);
    if (kk + 2 < NK) stage(cur, kk + 2);
    __builtin_amdgcn_sched_barrier(0);
  }

  // ---- epilogue: LDS-staged, coalesced ----
  float bv[4];
#pragma unroll
  for (int n = 0; n < 4; ++n) bv[n] = bias[n0 + wc * 64 + n * 16 + fr];

  OT* sE = (OT*)smem;  // [128][68] padded
#pragma unroll
  for (int h = 0; h < 2; ++h) {
    __syncthreads();
    if (wc == h) {
#pragma unroll
      for (int n = 0; n < 4; ++n) {
        const int colL = n * 16 + fr;  // 0..63 within half
#pragma unroll
        for (int m = 0; m < 4; ++m) {
          const int rbase = wr * 64 + m * 16 + g * 4;
#pragma unroll
          for (int r = 0; r < 4; ++r) {
            float v = acc[m][n][r] + bv[n];
            if (RELU) v = fmaxf(v, 0.f);
            sE[(rbase + r) * 68 + colL] = (OT)v;
          }
        }
      }
    }
    __syncthreads();
    const int rL0 = tid >> 4;          // 0..15
    const int colL = (tid & 15) * 4;   // 0..60
    const int gcol = n0 + h * 64 + colL;
#pragma unroll
    for (int p = 0; p < 8; ++p) {
      const int rowL = p * 16 + rL0;
      const int grow = m0 + rowL;
      if (grow < M) {
        if constexpr (sizeof(OT) == 4) {
          f32x4 v = *(const f32x4*)&sE[rowL * 68 + colL];
          *(f32x4*)((float*)out + (size_t)grow * 512 + gcol) = v;
        } else {
          bf16x4 v = *(const bf16x4*)&sE[rowL * 68 + colL];
          *(bf16x4*)((bf16_t*)out + (size_t)grow * 512 + gcol) = v;
          if (HAS8) {
            unsigned int u = 0;
#pragma unroll
            for (int i = 0; i < 4; ++i)
              u |= (unsigned int)f32_to_fp8((float)v[i]) << (8 * i);
            *(unsigned int*)(out8 + (size_t)grow * 512 + gcol) = u;
          }
        }
      }
    }
  }
}

extern "C" void kernel_launch(void* const* d_in, const int* in_sizes, int n_in,
                              void* d_out, int out_size, void* d_ws, size_t ws_size,
                              hipStream_t stream) {
  const float* x   = (const float*)d_in[0];
  const int*   ei  = (const int*)d_in[1];
  const float* Wl1 = (const float*)d_in[2];
  const float* Wr1 = (const float*)d_in[3];
  const float* b1  = (const float*)d_in[4];
  const float* Wl2 = (const float*)d_in[5];
  const float* Wr2 = (const float*)d_in[6];
  const float* b2  = (const float*)d_in[7];

  const int N = in_sizes[0] / 512;            // 50000
  const int E = in_sizes[1] / 2;              // 800000
  const int* srcp = ei;
  const int* dstp = ei + E;

  char* ws = (char*)d_ws;
  size_t off = 0;
  auto alloc = [&](size_t sz) -> char* {
    char* p = ws + off;
    off += sz;
    off = (off + 255) & ~(size_t)255;
    return p;
  };

  bf16_t* xb    = (bf16_t*)alloc((size_t)NPAD2 * 512 * 2);
  bf16_t* hb    = (bf16_t*)alloc((size_t)NPAD2 * 512 * 2);
  bf16_t* meanb = (bf16_t*)alloc((size_t)NPAD2 * 512 * 2);
  bf16_t* WB1   = (bf16_t*)alloc((size_t)512 * 1024 * 2);
  bf16_t* WB2   = (bf16_t*)alloc((size_t)512 * 1024 * 2);
  int* deg      = (int*)alloc((size_t)N * 4);
  int* rowS     = (int*)alloc((size_t)(N + 8) * 4);
  int* cursor   = (int*)alloc((size_t)N * 4);
  int* partial  = (int*)alloc(4096);
  int* colb     = (int*)alloc((size_t)E * 4);
  unsigned char* x8 = (unsigned char*)alloc((size_t)NPAD2 * 512);
  unsigned char* h8 = (unsigned char*)alloc((size_t)NPAD2 * 512);
  const bool useFp8 = (off <= ws_size);
  (void)n_in; (void)out_size;

  hipMemsetAsync(deg, 0, (size_t)N * 4, stream);

  const int degBlocks = (E + 255) / 256;  // 3125
  cvt_all_k<<<dim3(XBLOCKS + 512 + degBlocks), dim3(256), 0, stream>>>(
      x, xb, useFp8 ? x8 : nullptr, N * 512, Wl1, Wr1, WB1, Wl2, Wr2, WB2,
      dstp, deg, E);

  int NB = (N + 511) / 512;  // 98
  scan_part_k<<<dim3(NB), dim3(512), 0, stream>>>(deg, partial, N);
  scan_blk2_k<<<dim3(NB), dim3(512), 0, stream>>>(deg, partial, rowS, cursor, N, NB);
  scat_k<<<dim3((E + 255) / 256), dim3(256), 0, stream>>>(srcp, dstp, cursor, colb, E);

  dim3 agrid(NPAD2 / 4);
  dim3 grid(GEMM_BLOCKS);

  if (useFp8) {
    // layer 1 (gemm writes bf16 h AND packed fp8 h8 via coalesced epilogue)
    agg_k<true><<<agrid, dim3(256), 0, stream>>>(x8, rowS, colb, meanb, N);
    gemm_k<true, true, bf16_t><<<grid, dim3(256), 0, stream>>>(meanb, xb, WB1, b1, hb, h8, NPAD2);
    // layer 2
    agg_k<true><<<agrid, dim3(256), 0, stream>>>(h8, rowS, colb, meanb, N);
    gemm_k<false, false, float><<<grid, dim3(256), 0, stream>>>(meanb, hb, WB2, b2, (float*)d_out, nullptr, N);
  } else {
    // fallback: bf16 gather path
    agg_k<false><<<agrid, dim3(256), 0, stream>>>(xb, rowS, colb, meanb, N);
    gemm_k<true, false, bf16_t><<<grid, dim3(256), 0, stream>>>(meanb, xb, WB1, b1, hb, nullptr, NPAD2);
    agg_k<false><<<agrid, dim3(256), 0, stream>>>(hb, rowS, colb, meanb, N);
    gemm_k<false, false, float><<<grid, dim3(256), 0, stream>>>(meanb, hb, WB2, b2, (float*)d_out, nullptr, N);
  }
}